// Round 9
// baseline (66.754 us; speedup 1.0000x reference)
//
#include <hip/hip_runtime.h>
#include <hip/hip_fp16.h>

#define T_CTX 100
#define C_DIM 384
#define H_DIM 64

typedef _Float16 half8   __attribute__((ext_vector_type(8)));
typedef _Float16 half4_t __attribute__((ext_vector_type(4)));
typedef _Float16 half2_t __attribute__((ext_vector_type(2)));
typedef float    f32x4   __attribute__((ext_vector_type(4)));

// ---- LDS layout, units = halfs (2B) ----
// Persistent (phase2/3), 7 row-tiles (rows 0..111):
//   QH [7][2 kk][64 granule][8] @ 0      (7168 halfs)   granule = swz(LANE)
//   QL                          @ 7168   (7168)
//   KH [7][2 kk][64][8]         @ 14336  (7168)         swizzled granules
//   KL                          @ 21504  (7168)
//   VT [4 jh][4 kk][64][8]      @ 28672  (8192)         (unswizzled)
//   total 36864 halfs = 73728 B -> 2 blocks/CU
// Overlays @0 (dead regions at time of use):
//   XS: 2 buf x {hi [128][40], lo @ +5120} = 20480 halfs (R1/R6-proven)
//   PS: [7 wid][4 kk][64][8] halfs (14336), swizzled granules
#define QH_OFF 0
#define QL_OFF 7168
#define KH_OFF 14336
#define KL_OFF 21504
#define VT_OFF 28672
#define PS_OFF 0
#define SMEM_BYTES 73728

__global__ void prep_w_kernel(const float* __restrict__ Wq,
                              const float* __restrict__ Wk,
                              const float* __restrict__ Wv,
                              _Float16* __restrict__ wf_hi,
                              _Float16* __restrict__ wf_lo) {
    int idx = blockIdx.x * 256 + threadIdx.x;   // over 12*12*64 = 9216 frag-lanes
    if (idx >= 9216) return;
    int lane  = idx & 63;
    int chunk = (idx >> 6) % 12;
    int jt    = idx / (64 * 12);
    int col   = jt * 16 + (lane & 15);          // global N col 0..191 (q|k|v)
    const float* W = (col < 64) ? Wq : ((col < 128) ? Wk : Wv);
    int h = col & 63;
    int cbase = chunk * 32 + (lane >> 4) * 8;   // K index base
    #pragma unroll
    for (int e = 0; e < 8; ++e) {
        float f = W[(size_t)(cbase + e) * H_DIM + h];
        _Float16 hi = (_Float16)f;
        _Float16 lo = (_Float16)(f - (float)hi);
        size_t o = (size_t)idx * 8 + e;
        wf_hi[o] = hi;
        wf_lo[o] = lo;
    }
}

// 4 fp32 -> fp16 hi/lo half4 planes (producer-side, 1x per element)
__device__ inline void cvt4(f32x4 v, half4_t& hh, half4_t& ll) {
    #pragma unroll
    for (int u = 0; u < 4; ++u) {
        _Float16 h = (_Float16)v[u];
        hh[u] = h;
        ll[u] = (_Float16)(v[u] - (float)h);
    }
}

// swizzled Q/K-plane offset for element (row 0..111, h 0..63)
__device__ inline int qk_off(int row, int h) {
    int LANE = (row & 15) + ((h >> 3) & 3) * 16;
    int LS   = (LANE ^ (LANE >> 2)) & 63;
    return (row >> 4) * 1024 + ((h >> 5) & 1) * 512 + LS * 8 + (h & 7);
}

__global__ __launch_bounds__(512, 4)
void head_kernel(const float* __restrict__ x,
                 const _Float16* __restrict__ wf_hi,
                 const _Float16* __restrict__ wf_lo,
                 float* __restrict__ out) {
    extern __shared__ _Float16 sm[];

    const int b    = blockIdx.x;
    const int tid  = threadIdx.x;
    const int lane = tid & 63;
    const int wid  = tid >> 6;      // 8 waves
    const int l15  = lane & 15;
    const int lg   = lane >> 4;     // 0..3
    const int mh   = wid >> 2;      // row half
    const int nw   = wid & 3;
    const int NI   = (mh == 0) ? 4 : 3;   // mh=1 skips rows 112..127
    const bool isK = (nw >= 2);
    const int swl8 = ((lane ^ (lane >> 2)) & 63) * 8;   // swizzled read granule

    // wave -> B tiles (wf layout: tiles 0-3 q, 4-7 k, 8-11 v; tile stride 6144)
    int t0, t1;
    const _Float16 *pw0, *pw1, *pw2, *pw3;
    if (!isK) {
        t0 = nw * 2; t1 = t0 + 1;
        pw0 = wf_hi + (size_t)t0 * 6144;
        pw1 = wf_hi + (size_t)t1 * 6144;
        pw2 = wf_hi + (size_t)(8 + nw * 2) * 6144;      // v hi
        pw3 = wf_hi + (size_t)(9 + nw * 2) * 6144;
    } else {
        t0 = 4 + (nw - 2) * 2; t1 = t0 + 1;
        pw0 = wf_hi + (size_t)t0 * 6144;
        pw1 = wf_hi + (size_t)t1 * 6144;
        pw2 = wf_lo + (size_t)t0 * 6144;                // k lo
        pw3 = wf_lo + (size_t)t1 * 6144;
    }

    const float* xb = x + (size_t)b * T_CTX * C_DIM;

    // ================= phase 1: q,k,v = x @ W (R1/R6-proven staging) =================
    f32x4 acc0[4], acc1[4], acc2[4], acc3[4];
    #pragma unroll
    for (int i = 0; i < 4; ++i) {
        acc0[i] = (f32x4){0.f,0.f,0.f,0.f};
        acc1[i] = (f32x4){0.f,0.f,0.f,0.f};
        acc2[i] = (f32x4){0.f,0.f,0.f,0.f};
        acc3[i] = (f32x4){0.f,0.f,0.f,0.f};
    }

    // prologue: stage chunk 0 -> buf 0
    #pragma unroll
    for (int s = 0; s < 2; ++s) {
        int f4  = tid + s * 512;
        int row = f4 >> 3;
        int c4  = f4 & 7;
        f32x4 v = (f32x4){0.f, 0.f, 0.f, 0.f};
        if (row < T_CTX) v = *(const f32x4*)(xb + (size_t)row * C_DIM + c4 * 4);
        half4_t hh, ll;
        cvt4(v, hh, ll);
        int o = row * 40 + c4 * 4;
        *(half4_t*)(sm + o)        = hh;
        *(half4_t*)(sm + 5120 + o) = ll;
    }
    // preload W chunk 0 into registers
    half8 W0 = *(const half8*)(pw0 + lane * 8);
    half8 W1 = *(const half8*)(pw1 + lane * 8);
    half8 W2 = *(const half8*)(pw2 + lane * 8);
    half8 W3 = *(const half8*)(pw3 + lane * 8);
    __syncthreads();

    #pragma unroll 1
    for (int kc = 0; kc < 12; ++kc) {
        const int nk = kc + 1;
        f32x4 ld[2];
        half8 N0 = W0, N1 = W1, N2 = W2, N3 = W3;
        if (nk < 12) {   // issue next-chunk global loads + W prefetch early
            #pragma unroll
            for (int s = 0; s < 2; ++s) {
                int f4  = tid + s * 512;
                int row = f4 >> 3;
                int c4  = f4 & 7;
                ld[s] = (f32x4){0.f, 0.f, 0.f, 0.f};
                if (row < T_CTX)
                    ld[s] = *(const f32x4*)(xb + (size_t)row * C_DIM + nk * 32 + c4 * 4);
            }
            const int wo = nk * 512 + lane * 8;
            N0 = *(const half8*)(pw0 + wo);
            N1 = *(const half8*)(pw1 + wo);
            N2 = *(const half8*)(pw2 + wo);
            N3 = *(const half8*)(pw3 + wo);
        }

        const _Float16* xh = sm + (kc & 1) * 10240;
        const _Float16* xl = xh + 5120;
        #pragma unroll
        for (int i = 0; i < 4; ++i) {
            if (i >= NI) break;
            int row = mh * 64 + i * 16 + l15;
            int o = row * 40 + lg * 8;
            half8 ah = *(const half8*)(xh + o);
            half8 al = *(const half8*)(xl + o);
            // q (2-prod) / k (3-prod) on acc0/acc1; v (1-prod) on acc2/acc3
            acc0[i] = __builtin_amdgcn_mfma_f32_16x16x32_f16(ah, W0, acc0[i], 0, 0, 0);
            acc0[i] = __builtin_amdgcn_mfma_f32_16x16x32_f16(al, W0, acc0[i], 0, 0, 0);
            acc1[i] = __builtin_amdgcn_mfma_f32_16x16x32_f16(ah, W1, acc1[i], 0, 0, 0);
            acc1[i] = __builtin_amdgcn_mfma_f32_16x16x32_f16(al, W1, acc1[i], 0, 0, 0);
            if (!isK) {
                acc2[i] = __builtin_amdgcn_mfma_f32_16x16x32_f16(ah, W2, acc2[i], 0, 0, 0);
                acc3[i] = __builtin_amdgcn_mfma_f32_16x16x32_f16(ah, W3, acc3[i], 0, 0, 0);
            } else {
                acc0[i] = __builtin_amdgcn_mfma_f32_16x16x32_f16(ah, W2, acc0[i], 0, 0, 0);
                acc1[i] = __builtin_amdgcn_mfma_f32_16x16x32_f16(ah, W3, acc1[i], 0, 0, 0);
            }
        }

        if (nk < 12) {   // producer-side cvt + write next chunk into other buffer
            const int nb = (nk & 1) * 10240;
            #pragma unroll
            for (int s = 0; s < 2; ++s) {
                int f4  = tid + s * 512;
                int row = f4 >> 3;
                int c4  = f4 & 7;
                half4_t hh, ll;
                cvt4(ld[s], hh, ll);
                int o = row * 40 + c4 * 4;
                *(half4_t*)(sm + nb + o)        = hh;
                *(half4_t*)(sm + nb + 5120 + o) = ll;
            }
        }
        __syncthreads();
        W0 = N0; W1 = N1; W2 = N2; W3 = N3;
    }

    // VT zero-fill rows 112..127
    {
        int jh = tid >> 7;
        int w2 = (tid & 127) * 2;
        *(half2_t*)(sm + VT_OFF + jh * 2048 + 1792 + w2) =
            (half2_t){(_Float16)0.f, (_Float16)0.f};
    }

    // epilogue: scatter accs -> fragment-packed LDS (swizzled q/k granules)
    #pragma unroll
    for (int i = 0; i < 4; ++i) {
        if (i >= NI) break;
        #pragma unroll
        for (int r = 0; r < 4; ++r) {
            int row = mh * 64 + i * 16 + lg * 4 + r;   // time index 0..111
            if (!isK) {
                {   // q tile t0
                    int h = t0 * 16 + l15;
                    int off = qk_off(row, h);
                    float v0 = acc0[i][r];
                    _Float16 hh = (_Float16)v0;
                    sm[QH_OFF + off] = hh;
                    sm[QL_OFF + off] = (_Float16)(v0 - (float)hh);
                }
                {   // q tile t1
                    int h = t1 * 16 + l15;
                    int off = qk_off(row, h);
                    float v0 = acc1[i][r];
                    _Float16 hh = (_Float16)v0;
                    sm[QH_OFF + off] = hh;
                    sm[QL_OFF + off] = (_Float16)(v0 - (float)hh);
                }
                {   // v tile nw*2
                    int h = nw * 32 + l15;
                    int off = (h >> 4) * 2048 + (row >> 5) * 512
                            + (((row >> 3) & 3) * 16 + (h & 15)) * 8 + (row & 7);
                    sm[VT_OFF + off] = (_Float16)acc2[i][r];
                }
                {   // v tile nw*2+1
                    int h = nw * 32 + 16 + l15;
                    int off = (h >> 4) * 2048 + (row >> 5) * 512
                            + (((row >> 3) & 3) * 16 + (h & 15)) * 8 + (row & 7);
                    sm[VT_OFF + off] = (_Float16)acc3[i][r];
                }
            } else {
                {   // k tile t0
                    int h = (t0 - 4) * 16 + l15;
                    int off = qk_off(row, h);
                    float v0 = acc0[i][r];
                    _Float16 hh = (_Float16)v0;
                    sm[KH_OFF + off] = hh;
                    sm[KL_OFF + off] = (_Float16)(v0 - (float)hh);
                }
                {   // k tile t1
                    int h = (t1 - 4) * 16 + l15;
                    int off = qk_off(row, h);
                    float v0 = acc1[i][r];
                    _Float16 hh = (_Float16)v0;
                    sm[KH_OFF + off] = hh;
                    sm[KL_OFF + off] = (_Float16)(v0 - (float)hh);
                }
            }
        }
    }
    __syncthreads();

    // ================= phase 2: scores (split fp16), softmax (waves 0..6) ============
    f32x4 sacc[7];
    float rsum[4] = {0.f, 0.f, 0.f, 0.f};
    const float SC = 8.0f * 1.44269504088896f;   // fold scale*log2(e) for exp2

    if (wid < 7) {
        #pragma unroll
        for (int j = 0; j < 7; ++j) sacc[j] = (f32x4){0.f,0.f,0.f,0.f};
        #pragma unroll
        for (int kk = 0; kk < 2; ++kk) {
            half8 qh = *(const half8*)(sm + QH_OFF + wid * 1024 + kk * 512 + swl8);
            half8 ql = *(const half8*)(sm + QL_OFF + wid * 1024 + kk * 512 + swl8);
            #pragma unroll
            for (int j = 0; j < 7; ++j) {
                half8 kh = *(const half8*)(sm + KH_OFF + j * 1024 + kk * 512 + swl8);
                half8 kl = *(const half8*)(sm + KL_OFF + j * 1024 + kk * 512 + swl8);
                sacc[j] = __builtin_amdgcn_mfma_f32_16x16x32_f16(qh, kh, sacc[j], 0, 0, 0);
                sacc[j] = __builtin_amdgcn_mfma_f32_16x16x32_f16(ql, kh, sacc[j], 0, 0, 0);
                sacc[j] = __builtin_amdgcn_mfma_f32_16x16x32_f16(qh, kl, sacc[j], 0, 0, 0);
            }
        }
        float rmax[4] = {-1e30f, -1e30f, -1e30f, -1e30f};
        #pragma unroll
        for (int j = 0; j < 7; ++j) {
            int key = j * 16 + l15;
            #pragma unroll
            for (int r = 0; r < 4; ++r) {
                int row = wid * 16 + lg * 4 + r;
                // faithful bug: x sqrt(64)=8 (folded with log2e); causal + key<100 mask
                float s = (key <= row && key < T_CTX) ? sacc[j][r] * SC : -1e30f;
                sacc[j][r] = s;
                rmax[r] = fmaxf(rmax[r], s);
            }
        }
        #pragma unroll
        for (int r = 0; r < 4; ++r) {
            #pragma unroll
            for (int d = 1; d < 16; d <<= 1)
                rmax[r] = fmaxf(rmax[r], __shfl_xor(rmax[r], d, 64));
            rsum[r] = rmax[r];   // stash rmax across the barrier
        }
    }
    __syncthreads();   // all q/k reads done before PS overlays that region

    if (wid < 7) {
        float rmax[4];
        #pragma unroll
        for (int r = 0; r < 4; ++r) { rmax[r] = rsum[r]; rsum[r] = 0.f; }
        #pragma unroll
        for (int j = 0; j < 7; ++j) {
            int key = j * 16 + l15;
            #pragma unroll
            for (int r = 0; r < 4; ++r) {
                float p = exp2f(sacc[j][r] - rmax[r]);   // masked -> 0
                rsum[r] += p;
                int a = lg * 4 + r;
                int LANE = ((key >> 3) & 3) * 16 + a;
                int LS = (LANE ^ (LANE >> 2)) & 63;
                int off = wid * 2048 + (key >> 5) * 512 + LS * 8 + (key & 7);
                sm[PS_OFF + off] = (_Float16)p;
            }
        }
        #pragma unroll
        for (int r = 0; r < 4; ++r) {                   // zero pad keys 112..127
            int key = 112 + l15;
            int a = lg * 4 + r;
            int LANE = ((key >> 3) & 3) * 16 + a;
            int LS = (LANE ^ (LANE >> 2)) & 63;
            int off = wid * 2048 + (key >> 5) * 512 + LS * 8 + (key & 7);
            sm[PS_OFF + off] = (_Float16)0.f;
            #pragma unroll
            for (int d = 1; d < 16; d <<= 1)
                rsum[r] += __shfl_xor(rsum[r], d, 64);
        }
    }
    __syncthreads();

    // ================= phase 3: out = (P @ V) / rowsum (waves 0..6) ===================
    if (wid < 7) {
        f32x4 oacc[4];
        #pragma unroll
        for (int j = 0; j < 4; ++j) oacc[j] = (f32x4){0.f,0.f,0.f,0.f};
        #pragma unroll
        for (int kk = 0; kk < 4; ++kk) {
            half8 pa = *(const half8*)(sm + PS_OFF + wid * 2048 + kk * 512 + swl8);
            #pragma unroll
            for (int jh = 0; jh < 4; ++jh) {
                half8 vb = *(const half8*)(sm + VT_OFF + jh * 2048 + kk * 512 + lane * 8);
                oacc[jh] = __builtin_amdgcn_mfma_f32_16x16x32_f16(pa, vb, oacc[jh], 0, 0, 0);
            }
        }
        float rinv[4];
        #pragma unroll
        for (int r = 0; r < 4; ++r) rinv[r] = 1.0f / rsum[r];
        #pragma unroll
        for (int jh = 0; jh < 4; ++jh) {
            #pragma unroll
            for (int r = 0; r < 4; ++r) {
                int t = wid * 16 + lg * 4 + r;
                if (t < T_CTX)
                    out[((size_t)b * T_CTX + t) * H_DIM + jh * 16 + l15] = oacc[jh][r] * rinv[r];
            }
        }
    }
}

extern "C" void kernel_launch(void* const* d_in, const int* in_sizes, int n_in,
                              void* d_out, int out_size, void* d_ws, size_t ws_size,
                              hipStream_t stream) {
    const float* x  = (const float*)d_in[0];
    const float* Wq = (const float*)d_in[1];
    const float* Wk = (const float*)d_in[2];
    const float* Wv = (const float*)d_in[3];

    _Float16* wf_hi = (_Float16*)d_ws;                 // 12*12*64*8 halfs = 147456 B
    _Float16* wf_lo = wf_hi + (size_t)9216 * 8;        // total ws use: 294912 B

    prep_w_kernel<<<36, 256, 0, stream>>>(Wq, Wk, Wv, wf_hi, wf_lo);

    (void)hipFuncSetAttribute((const void*)head_kernel,
                              hipFuncAttributeMaxDynamicSharedMemorySize, SMEM_BYTES);
    head_kernel<<<1024, 512, SMEM_BYTES, stream>>>(x, wf_hi, wf_lo, (float*)d_out);
}

// Round 10
// 64.973 us; speedup vs baseline: 1.0274x; 1.0274x over previous
//
#include <hip/hip_runtime.h>
#include <hip/hip_fp16.h>

#define T_CTX 100
#define C_DIM 384
#define H_DIM 64

typedef _Float16 half8   __attribute__((ext_vector_type(8)));
typedef _Float16 half4_t __attribute__((ext_vector_type(4)));
typedef _Float16 half2_t __attribute__((ext_vector_type(2)));
typedef float    f32x4   __attribute__((ext_vector_type(4)));

// ---- LDS layout, units = halfs (2B) ---- (R6-proven)
//   QH [7][2 kk][64][8] @ 0      (7168 halfs)
//   QL                  @ 7168   (7168)
//   KH [7][2 kk][64][8] @ 14336  (7168)
//   KL                  @ 21504  (7168)
//   VT [4 jh][4 kk][64][8] @ 28672 (8192)
//   total 36864 halfs = 73728 B -> 2 blocks/CU
// Overlays @0: XS 2 buf x {hi [128][40], lo @ +5120}; PS [7 wid][4 kk][64][8]
#define QH_OFF 0
#define QL_OFF 7168
#define KH_OFF 14336
#define KL_OFF 21504
#define VT_OFF 28672
#define PS_OFF 0
#define SMEM_BYTES 73728

__global__ void prep_w_kernel(const float* __restrict__ Wq,
                              const float* __restrict__ Wk,
                              const float* __restrict__ Wv,
                              _Float16* __restrict__ wf_hi,
                              _Float16* __restrict__ wf_lo) {
    int idx = blockIdx.x * 256 + threadIdx.x;   // over 12*12*64 = 9216 frag-lanes
    if (idx >= 9216) return;
    int lane  = idx & 63;
    int chunk = (idx >> 6) % 12;
    int jt    = idx / (64 * 12);
    int col   = jt * 16 + (lane & 15);          // global N col 0..191 (q|k|v)
    const float* W = (col < 64) ? Wq : ((col < 128) ? Wk : Wv);
    int h = col & 63;
    int cbase = chunk * 32 + (lane >> 4) * 8;   // K index base
    #pragma unroll
    for (int e = 0; e < 8; ++e) {
        float f = W[(size_t)(cbase + e) * H_DIM + h];
        _Float16 hi = (_Float16)f;
        _Float16 lo = (_Float16)(f - (float)hi);
        size_t o = (size_t)idx * 8 + e;
        wf_hi[o] = hi;
        wf_lo[o] = lo;
    }
}

// 4 fp32 -> fp16 hi/lo half4 planes (producer-side, 1x per element)
__device__ inline void cvt4(f32x4 v, half4_t& hh, half4_t& ll) {
    #pragma unroll
    for (int u = 0; u < 4; ++u) {
        _Float16 h = (_Float16)v[u];
        hh[u] = h;
        ll[u] = (_Float16)(v[u] - (float)h);
    }
}

// plain (R6) fragment-packed offset for q/k element (row 0..111, h 0..63)
__device__ inline int qk_off(int row, int h) {
    return (row >> 4) * 1024 + ((h >> 5) & 1) * 512
         + (((h >> 3) & 3) * 16 + (row & 15)) * 8 + (h & 7);
}

__global__ __launch_bounds__(512, 4)
void head_kernel(const float* __restrict__ x,
                 const _Float16* __restrict__ wf_hi,
                 const _Float16* __restrict__ wf_lo,
                 float* __restrict__ out) {
    extern __shared__ _Float16 sm[];

    const int b    = blockIdx.x;
    const int tid  = threadIdx.x;
    const int lane = tid & 63;
    const int wid  = tid >> 6;      // 8 waves
    const int l15  = lane & 15;
    const int lg   = lane >> 4;     // 0..3
    const int mh   = wid >> 2;      // row half
    const int nw   = wid & 3;
    const int NI   = (mh == 0) ? 4 : 3;   // mh=1 skips rows 112..127
    const bool isK = (nw >= 2);
    const int ln8  = lane * 8;

    // wave -> B tiles (wf layout: tiles 0-3 q, 4-7 k, 8-11 v; tile stride 6144)
    int t0, t1;
    const _Float16 *pw0, *pw1, *pw2, *pw3;
    if (!isK) {
        t0 = nw * 2; t1 = t0 + 1;
        pw0 = wf_hi + (size_t)t0 * 6144;
        pw1 = wf_hi + (size_t)t1 * 6144;
        pw2 = wf_hi + (size_t)(8 + nw * 2) * 6144;      // v hi
        pw3 = wf_hi + (size_t)(9 + nw * 2) * 6144;
    } else {
        t0 = 4 + (nw - 2) * 2; t1 = t0 + 1;
        pw0 = wf_hi + (size_t)t0 * 6144;
        pw1 = wf_hi + (size_t)t1 * 6144;
        pw2 = wf_lo + (size_t)t0 * 6144;                // k lo
        pw3 = wf_lo + (size_t)t1 * 6144;
    }

    const float* xb = x + (size_t)b * T_CTX * C_DIM;

    // ================= phase 1: q,k,v = x @ W (R6-proven staging) =====================
    f32x4 acc0[4], acc1[4], acc2[4], acc3[4];
    #pragma unroll
    for (int i = 0; i < 4; ++i) {
        acc0[i] = (f32x4){0.f,0.f,0.f,0.f};
        acc1[i] = (f32x4){0.f,0.f,0.f,0.f};
        acc2[i] = (f32x4){0.f,0.f,0.f,0.f};
        acc3[i] = (f32x4){0.f,0.f,0.f,0.f};
    }

    // prologue: stage chunk 0 -> buf 0
    #pragma unroll
    for (int s = 0; s < 2; ++s) {
        int f4  = tid + s * 512;
        int row = f4 >> 3;
        int c4  = f4 & 7;
        f32x4 v = (f32x4){0.f, 0.f, 0.f, 0.f};
        if (row < T_CTX) v = *(const f32x4*)(xb + (size_t)row * C_DIM + c4 * 4);
        half4_t hh, ll;
        cvt4(v, hh, ll);
        int o = row * 40 + c4 * 4;
        *(half4_t*)(sm + o)        = hh;
        *(half4_t*)(sm + 5120 + o) = ll;
    }
    // preload W chunk 0 into registers
    half8 W0 = *(const half8*)(pw0 + ln8);
    half8 W1 = *(const half8*)(pw1 + ln8);
    half8 W2 = *(const half8*)(pw2 + ln8);
    half8 W3 = *(const half8*)(pw3 + ln8);
    __syncthreads();

    #pragma unroll 1
    for (int kc = 0; kc < 12; ++kc) {
        const int nk = kc + 1;
        f32x4 ld[2];
        half8 N0 = W0, N1 = W1, N2 = W2, N3 = W3;
        if (nk < 12) {   // issue next-chunk global loads + W prefetch early
            #pragma unroll
            for (int s = 0; s < 2; ++s) {
                int f4  = tid + s * 512;
                int row = f4 >> 3;
                int c4  = f4 & 7;
                ld[s] = (f32x4){0.f, 0.f, 0.f, 0.f};
                if (row < T_CTX)
                    ld[s] = *(const f32x4*)(xb + (size_t)row * C_DIM + nk * 32 + c4 * 4);
            }
            const int wo = nk * 512 + ln8;
            N0 = *(const half8*)(pw0 + wo);
            N1 = *(const half8*)(pw1 + wo);
            N2 = *(const half8*)(pw2 + wo);
            N3 = *(const half8*)(pw3 + wo);
        }

        const _Float16* xh = sm + (kc & 1) * 10240;
        const _Float16* xl = xh + 5120;
        #pragma unroll
        for (int i = 0; i < 4; ++i) {
            if (i >= NI) break;
            int row = mh * 64 + i * 16 + l15;
            int o = row * 40 + lg * 8;
            half8 ah = *(const half8*)(xh + o);
            half8 al = *(const half8*)(xl + o);
            // q (2-prod) / k (3-prod) on acc0/acc1; v (1-prod) on acc2/acc3
            acc0[i] = __builtin_amdgcn_mfma_f32_16x16x32_f16(ah, W0, acc0[i], 0, 0, 0);
            acc0[i] = __builtin_amdgcn_mfma_f32_16x16x32_f16(al, W0, acc0[i], 0, 0, 0);
            acc1[i] = __builtin_amdgcn_mfma_f32_16x16x32_f16(ah, W1, acc1[i], 0, 0, 0);
            acc1[i] = __builtin_amdgcn_mfma_f32_16x16x32_f16(al, W1, acc1[i], 0, 0, 0);
            if (!isK) {
                acc2[i] = __builtin_amdgcn_mfma_f32_16x16x32_f16(ah, W2, acc2[i], 0, 0, 0);
                acc3[i] = __builtin_amdgcn_mfma_f32_16x16x32_f16(ah, W3, acc3[i], 0, 0, 0);
            } else {
                acc0[i] = __builtin_amdgcn_mfma_f32_16x16x32_f16(ah, W2, acc0[i], 0, 0, 0);
                acc1[i] = __builtin_amdgcn_mfma_f32_16x16x32_f16(ah, W3, acc1[i], 0, 0, 0);
            }
        }

        if (nk < 12) {   // producer-side cvt + write next chunk into other buffer
            const int nb = (nk & 1) * 10240;
            #pragma unroll
            for (int s = 0; s < 2; ++s) {
                int f4  = tid + s * 512;
                int row = f4 >> 3;
                int c4  = f4 & 7;
                half4_t hh, ll;
                cvt4(ld[s], hh, ll);
                int o = row * 40 + c4 * 4;
                *(half4_t*)(sm + nb + o)        = hh;
                *(half4_t*)(sm + nb + 5120 + o) = ll;
            }
        }
        __syncthreads();
        W0 = N0; W1 = N1; W2 = N2; W3 = N3;
    }

    // VT zero-fill rows 112..127
    {
        int jh = tid >> 7;
        int w2 = (tid & 127) * 2;
        *(half2_t*)(sm + VT_OFF + jh * 2048 + 1792 + w2) =
            (half2_t){(_Float16)0.f, (_Float16)0.f};
    }

    // epilogue: scatter accs -> fragment-packed LDS (plain R6 offsets)
    #pragma unroll
    for (int i = 0; i < 4; ++i) {
        if (i >= NI) break;
        #pragma unroll
        for (int r = 0; r < 4; ++r) {
            int row = mh * 64 + i * 16 + lg * 4 + r;   // time index 0..111
            if (!isK) {
                {   // q tile t0
                    int h = t0 * 16 + l15;
                    int off = qk_off(row, h);
                    float v0 = acc0[i][r];
                    _Float16 hh = (_Float16)v0;
                    sm[QH_OFF + off] = hh;
                    sm[QL_OFF + off] = (_Float16)(v0 - (float)hh);
                }
                {   // q tile t1
                    int h = t1 * 16 + l15;
                    int off = qk_off(row, h);
                    float v0 = acc1[i][r];
                    _Float16 hh = (_Float16)v0;
                    sm[QH_OFF + off] = hh;
                    sm[QL_OFF + off] = (_Float16)(v0 - (float)hh);
                }
                {   // v tile nw*2
                    int h = nw * 32 + l15;
                    int off = (h >> 4) * 2048 + (row >> 5) * 512
                            + (((row >> 3) & 3) * 16 + (h & 15)) * 8 + (row & 7);
                    sm[VT_OFF + off] = (_Float16)acc2[i][r];
                }
                {   // v tile nw*2+1
                    int h = nw * 32 + 16 + l15;
                    int off = (h >> 4) * 2048 + (row >> 5) * 512
                            + (((row >> 3) & 3) * 16 + (h & 15)) * 8 + (row & 7);
                    sm[VT_OFF + off] = (_Float16)acc3[i][r];
                }
            } else {
                {   // k tile t0
                    int h = (t0 - 4) * 16 + l15;
                    int off = qk_off(row, h);
                    float v0 = acc0[i][r];
                    _Float16 hh = (_Float16)v0;
                    sm[KH_OFF + off] = hh;
                    sm[KL_OFF + off] = (_Float16)(v0 - (float)hh);
                }
                {   // k tile t1
                    int h = (t1 - 4) * 16 + l15;
                    int off = qk_off(row, h);
                    float v0 = acc1[i][r];
                    _Float16 hh = (_Float16)v0;
                    sm[KH_OFF + off] = hh;
                    sm[KL_OFF + off] = (_Float16)(v0 - (float)hh);
                }
            }
        }
    }
    __syncthreads();

    // ====== phase 2: scores (split fp16) with CAUSAL SKIP (j <= wid), softmax ========
    f32x4 sacc[7];
    float rsum[4] = {0.f, 0.f, 0.f, 0.f};
    const float SC = 8.0f * 1.44269504088896f;   // fold scale*log2(e) for exp2

    if (wid < 7) {
        #pragma unroll
        for (int j = 0; j < 7; ++j) sacc[j] = (f32x4){0.f,0.f,0.f,0.f};
        #pragma unroll
        for (int kk = 0; kk < 2; ++kk) {
            half8 qh = *(const half8*)(sm + QH_OFF + wid * 1024 + kk * 512 + ln8);
            half8 ql = *(const half8*)(sm + QL_OFF + wid * 1024 + kk * 512 + ln8);
            #pragma unroll
            for (int j = 0; j < 7; ++j) {
                if (j > wid) break;                       // causal: keys j*16 > row
                half8 kh = *(const half8*)(sm + KH_OFF + j * 1024 + kk * 512 + ln8);
                half8 kl = *(const half8*)(sm + KL_OFF + j * 1024 + kk * 512 + ln8);
                sacc[j] = __builtin_amdgcn_mfma_f32_16x16x32_f16(qh, kh, sacc[j], 0, 0, 0);
                sacc[j] = __builtin_amdgcn_mfma_f32_16x16x32_f16(ql, kh, sacc[j], 0, 0, 0);
                sacc[j] = __builtin_amdgcn_mfma_f32_16x16x32_f16(qh, kl, sacc[j], 0, 0, 0);
            }
        }
        float rmax[4] = {-1e30f, -1e30f, -1e30f, -1e30f};
        #pragma unroll
        for (int j = 0; j < 7; ++j) {
            if (j > wid) break;
            int key = j * 16 + l15;
            #pragma unroll
            for (int r = 0; r < 4; ++r) {
                int row = wid * 16 + lg * 4 + r;
                // faithful bug: x sqrt(64)=8 (folded with log2e); causal + key<100 mask
                float s = (key <= row && key < T_CTX) ? sacc[j][r] * SC : -1e30f;
                sacc[j][r] = s;
                rmax[r] = fmaxf(rmax[r], s);
            }
        }
        #pragma unroll
        for (int r = 0; r < 4; ++r) {
            #pragma unroll
            for (int d = 1; d < 16; d <<= 1)
                rmax[r] = fmaxf(rmax[r], __shfl_xor(rmax[r], d, 64));
            rsum[r] = rmax[r];   // stash rmax across the barrier
        }
    }
    __syncthreads();   // all q/k reads done before PS overlays that region

    if (wid < 7) {
        float rmax[4];
        #pragma unroll
        for (int r = 0; r < 4; ++r) { rmax[r] = rsum[r]; rsum[r] = 0.f; }
        #pragma unroll
        for (int j = 0; j < 7; ++j) {
            if (j > wid) break;
            int key = j * 16 + l15;
            #pragma unroll
            for (int r = 0; r < 4; ++r) {
                float p = exp2f(sacc[j][r] - rmax[r]);   // masked -> 0
                rsum[r] += p;
                int a = lg * 4 + r;
                int off = wid * 2048 + (key >> 5) * 512
                        + (((key >> 3) & 3) * 16 + a) * 8 + (key & 7);
                sm[PS_OFF + off] = (_Float16)p;
            }
        }
        if ((wid & 1) == 0) {   // zero-fill the partially-read tile j = wid+1
            int key = (wid + 1) * 16 + l15;
            #pragma unroll
            for (int r = 0; r < 4; ++r) {
                int a = lg * 4 + r;
                int off = wid * 2048 + (key >> 5) * 512
                        + (((key >> 3) & 3) * 16 + a) * 8 + (key & 7);
                sm[PS_OFF + off] = (_Float16)0.f;
            }
        }
        #pragma unroll
        for (int r = 0; r < 4; ++r) {
            #pragma unroll
            for (int d = 1; d < 16; d <<= 1)
                rsum[r] += __shfl_xor(rsum[r], d, 64);
        }
    }
    __syncthreads();

    // ====== phase 3: out = (P @ V) / rowsum, CAUSAL SKIP (kk <= wid>>1) ==============
    if (wid < 7) {
        f32x4 oacc[4];
        #pragma unroll
        for (int j = 0; j < 4; ++j) oacc[j] = (f32x4){0.f,0.f,0.f,0.f};
        const int kkmax = wid >> 1;
        #pragma unroll
        for (int kk = 0; kk < 4; ++kk) {
            if (kk > kkmax) break;
            half8 pa = *(const half8*)(sm + PS_OFF + wid * 2048 + kk * 512 + ln8);
            #pragma unroll
            for (int jh = 0; jh < 4; ++jh) {
                half8 vb = *(const half8*)(sm + VT_OFF + jh * 2048 + kk * 512 + ln8);
                oacc[jh] = __builtin_amdgcn_mfma_f32_16x16x32_f16(pa, vb, oacc[jh], 0, 0, 0);
            }
        }
        float rinv[4];
        #pragma unroll
        for (int r = 0; r < 4; ++r) rinv[r] = 1.0f / rsum[r];
        #pragma unroll
        for (int jh = 0; jh < 4; ++jh) {
            #pragma unroll
            for (int r = 0; r < 4; ++r) {
                int t = wid * 16 + lg * 4 + r;
                if (t < T_CTX)
                    out[((size_t)b * T_CTX + t) * H_DIM + jh * 16 + l15] = oacc[jh][r] * rinv[r];
            }
        }
    }
}

extern "C" void kernel_launch(void* const* d_in, const int* in_sizes, int n_in,
                              void* d_out, int out_size, void* d_ws, size_t ws_size,
                              hipStream_t stream) {
    const float* x  = (const float*)d_in[0];
    const float* Wq = (const float*)d_in[1];
    const float* Wk = (const float*)d_in[2];
    const float* Wv = (const float*)d_in[3];

    _Float16* wf_hi = (_Float16*)d_ws;                 // 12*12*64*8 halfs = 147456 B
    _Float16* wf_lo = wf_hi + (size_t)9216 * 8;        // total ws use: 294912 B

    prep_w_kernel<<<36, 256, 0, stream>>>(Wq, Wk, Wv, wf_hi, wf_lo);

    (void)hipFuncSetAttribute((const void*)head_kernel,
                              hipFuncAttributeMaxDynamicSharedMemorySize, SMEM_BYTES);
    head_kernel<<<1024, 512, SMEM_BYTES, stream>>>(x, wf_hi, wf_lo, (float*)d_out);
}

// Round 12
// 64.527 us; speedup vs baseline: 1.0345x; 1.0069x over previous
//
#include <hip/hip_runtime.h>
#include <hip/hip_fp16.h>

#define T_CTX 100
#define C_DIM 384
#define H_DIM 64

typedef _Float16 half8   __attribute__((ext_vector_type(8)));
typedef _Float16 half4_t __attribute__((ext_vector_type(4)));
typedef _Float16 half2_t __attribute__((ext_vector_type(2)));
typedef float    f32x4   __attribute__((ext_vector_type(4)));

// ---- LDS layout, units = halfs (2B) ----
// Persistent (phase2/3), 7 row-tiles (rows 0..111):
//   QH [7][2 kk][64][8] @ 0      (7168 halfs)
//   QL                  @ 7168   (7168)
//   KH [7][2 kk][64][8] @ 14336  (7168)
//   KL                  @ 21504  (7168)
//   VT [4 jh][4 kk][64][8] @ 28672 (8192)
//   total 36864 halfs = 73728 B -> 2 blocks/CU
// Overlays @0 (dead regions at time of use):
//   XS (R1-proven): 2 buf x {hi [128][40], lo @ +5120} = 20480 halfs (40960 B)
//   PS: [7 wid][4 kk][64][8] halfs (14336)
#define QH_OFF 0
#define QL_OFF 7168
#define KH_OFF 14336
#define KL_OFF 21504
#define VT_OFF 28672
#define PS_OFF 0
#define SMEM_BYTES 73728

__global__ void prep_w_kernel(const float* __restrict__ Wq,
                              const float* __restrict__ Wk,
                              const float* __restrict__ Wv,
                              _Float16* __restrict__ wf_hi,
                              _Float16* __restrict__ wf_lo) {
    int idx = blockIdx.x * 256 + threadIdx.x;   // over 12*12*64 = 9216 frag-lanes
    if (idx >= 9216) return;
    int lane  = idx & 63;
    int chunk = (idx >> 6) % 12;
    int jt    = idx / (64 * 12);
    int col   = jt * 16 + (lane & 15);          // global N col 0..191 (q|k|v)
    const float* W = (col < 64) ? Wq : ((col < 128) ? Wk : Wv);
    int h = col & 63;
    int cbase = chunk * 32 + (lane >> 4) * 8;   // K index base
    #pragma unroll
    for (int e = 0; e < 8; ++e) {
        float f = W[(size_t)(cbase + e) * H_DIM + h];
        _Float16 hi = (_Float16)f;
        _Float16 lo = (_Float16)(f - (float)hi);
        size_t o = (size_t)idx * 8 + e;
        wf_hi[o] = hi;
        wf_lo[o] = lo;
    }
}

// 4 fp32 -> fp16 hi/lo half4 planes (producer-side, 1x per element)
__device__ inline void cvt4(f32x4 v, half4_t& hh, half4_t& ll) {
    #pragma unroll
    for (int u = 0; u < 4; ++u) {
        _Float16 h = (_Float16)v[u];
        hh[u] = h;
        ll[u] = (_Float16)(v[u] - (float)h);
    }
}

__global__ __launch_bounds__(512, 4)
void head_kernel(const float* __restrict__ x,
                 const _Float16* __restrict__ wf_hi,
                 const _Float16* __restrict__ wf_lo,
                 float* __restrict__ out) {
    extern __shared__ _Float16 sm[];

    const int b    = blockIdx.x;
    const int tid  = threadIdx.x;
    const int lane = tid & 63;
    const int wid  = tid >> 6;      // 8 waves
    const int l15  = lane & 15;
    const int lg   = lane >> 4;     // 0..3
    const int mh   = wid >> 2;      // row half
    const int nw   = wid & 3;
    const int NI   = (mh == 0) ? 4 : 3;   // mh=1 skips rows 112..127
    const bool isK = (nw >= 2);

    // wave -> B tiles (wf layout: tiles 0-3 q, 4-7 k, 8-11 v; tile stride 6144)
    int t0, t1;
    const _Float16 *pw0, *pw1, *pw2, *pw3;
    if (!isK) {
        t0 = nw * 2; t1 = t0 + 1;
        pw0 = wf_hi + (size_t)t0 * 6144;
        pw1 = wf_hi + (size_t)t1 * 6144;
        pw2 = wf_hi + (size_t)(8 + nw * 2) * 6144;      // v hi
        pw3 = wf_hi + (size_t)(9 + nw * 2) * 6144;
    } else {
        t0 = 4 + (nw - 2) * 2; t1 = t0 + 1;
        pw0 = wf_hi + (size_t)t0 * 6144;
        pw1 = wf_hi + (size_t)t1 * 6144;
        pw2 = wf_lo + (size_t)t0 * 6144;                // k lo
        pw3 = wf_lo + (size_t)t1 * 6144;
    }

    const float* xb = x + (size_t)b * T_CTX * C_DIM;

    // ================= phase 1: q,k,v = x @ W (R1-proven fp16 hi/lo staging) =========
    f32x4 acc0[4], acc1[4], acc2[4], acc3[4];
    #pragma unroll
    for (int i = 0; i < 4; ++i) {
        acc0[i] = (f32x4){0.f,0.f,0.f,0.f};
        acc1[i] = (f32x4){0.f,0.f,0.f,0.f};
        acc2[i] = (f32x4){0.f,0.f,0.f,0.f};
        acc3[i] = (f32x4){0.f,0.f,0.f,0.f};
    }

    // prologue: stage chunk 0 -> buf 0
    #pragma unroll
    for (int s = 0; s < 2; ++s) {
        int f4  = tid + s * 512;
        int row = f4 >> 3;
        int c4  = f4 & 7;
        f32x4 v = (f32x4){0.f, 0.f, 0.f, 0.f};
        if (row < T_CTX) v = *(const f32x4*)(xb + (size_t)row * C_DIM + c4 * 4);
        half4_t hh, ll;
        cvt4(v, hh, ll);
        int o = row * 40 + c4 * 4;
        *(half4_t*)(sm + o)        = hh;
        *(half4_t*)(sm + 5120 + o) = ll;
    }
    // preload W chunk 0 into registers
    half8 W0 = *(const half8*)(pw0 + lane * 8);
    half8 W1 = *(const half8*)(pw1 + lane * 8);
    half8 W2 = *(const half8*)(pw2 + lane * 8);
    half8 W3 = *(const half8*)(pw3 + lane * 8);
    __syncthreads();

    #pragma unroll 1
    for (int kc = 0; kc < 12; ++kc) {
        const int nk = kc + 1;
        f32x4 ld[2];
        half8 N0 = W0, N1 = W1, N2 = W2, N3 = W3;
        if (nk < 12) {   // issue next-chunk global loads + W prefetch early
            #pragma unroll
            for (int s = 0; s < 2; ++s) {
                int f4  = tid + s * 512;
                int row = f4 >> 3;
                int c4  = f4 & 7;
                ld[s] = (f32x4){0.f, 0.f, 0.f, 0.f};
                if (row < T_CTX)
                    ld[s] = *(const f32x4*)(xb + (size_t)row * C_DIM + nk * 32 + c4 * 4);
            }
            const int wo = nk * 512 + lane * 8;
            N0 = *(const half8*)(pw0 + wo);
            N1 = *(const half8*)(pw1 + wo);
            N2 = *(const half8*)(pw2 + wo);
            N3 = *(const half8*)(pw3 + wo);
        }

        const _Float16* xh = sm + (kc & 1) * 10240;
        const _Float16* xl = xh + 5120;
        #pragma unroll
        for (int i = 0; i < 4; ++i) {
            if (i >= NI) break;
            int row = mh * 64 + i * 16 + l15;
            int o = row * 40 + lg * 8;
            half8 ah = *(const half8*)(xh + o);
            half8 al = *(const half8*)(xl + o);
            // q (2-prod) / k (3-prod) on acc0/acc1; v (1-prod) on acc2/acc3
            acc0[i] = __builtin_amdgcn_mfma_f32_16x16x32_f16(ah, W0, acc0[i], 0, 0, 0);
            acc0[i] = __builtin_amdgcn_mfma_f32_16x16x32_f16(al, W0, acc0[i], 0, 0, 0);
            acc1[i] = __builtin_amdgcn_mfma_f32_16x16x32_f16(ah, W1, acc1[i], 0, 0, 0);
            acc1[i] = __builtin_amdgcn_mfma_f32_16x16x32_f16(al, W1, acc1[i], 0, 0, 0);
            if (!isK) {
                acc2[i] = __builtin_amdgcn_mfma_f32_16x16x32_f16(ah, W2, acc2[i], 0, 0, 0);
                acc3[i] = __builtin_amdgcn_mfma_f32_16x16x32_f16(ah, W3, acc3[i], 0, 0, 0);
            } else {
                acc0[i] = __builtin_amdgcn_mfma_f32_16x16x32_f16(ah, W2, acc0[i], 0, 0, 0);
                acc1[i] = __builtin_amdgcn_mfma_f32_16x16x32_f16(ah, W3, acc1[i], 0, 0, 0);
            }
        }

        if (nk < 12) {   // producer-side cvt + write next chunk into other buffer
            const int nb = (nk & 1) * 10240;
            #pragma unroll
            for (int s = 0; s < 2; ++s) {
                int f4  = tid + s * 512;
                int row = f4 >> 3;
                int c4  = f4 & 7;
                half4_t hh, ll;
                cvt4(ld[s], hh, ll);
                int o = row * 40 + c4 * 4;
                *(half4_t*)(sm + nb + o)        = hh;
                *(half4_t*)(sm + nb + 5120 + o) = ll;
            }
        }
        __syncthreads();
        W0 = N0; W1 = N1; W2 = N2; W3 = N3;
    }

    // VT zero-fill rows 112..127
    {
        int jh = tid >> 7;
        int w2 = (tid & 127) * 2;
        *(half2_t*)(sm + VT_OFF + jh * 2048 + 1792 + w2) =
            (half2_t){(_Float16)0.f, (_Float16)0.f};
    }

    // epilogue: scatter accs -> fragment-packed LDS (XS dead)
    #pragma unroll
    for (int i = 0; i < 4; ++i) {
        if (i >= NI) break;
        #pragma unroll
        for (int r = 0; r < 4; ++r) {
            int row = mh * 64 + i * 16 + lg * 4 + r;   // time index 0..111
            if (!isK) {
                {   // q tile t0
                    int h = t0 * 16 + l15;
                    int off = (row >> 4) * 1024 + (h >> 5) * 512
                            + (((h >> 3) & 3) * 16 + (row & 15)) * 8 + (h & 7);
                    float v0 = acc0[i][r];
                    _Float16 hh = (_Float16)v0;
                    sm[QH_OFF + off] = hh;
                    sm[QL_OFF + off] = (_Float16)(v0 - (float)hh);
                }
                {   // q tile t1
                    int h = t1 * 16 + l15;
                    int off = (row >> 4) * 1024 + (h >> 5) * 512
                            + (((h >> 3) & 3) * 16 + (row & 15)) * 8 + (h & 7);
                    float v0 = acc1[i][r];
                    _Float16 hh = (_Float16)v0;
                    sm[QH_OFF + off] = hh;
                    sm[QL_OFF + off] = (_Float16)(v0 - (float)hh);
                }
                {   // v tile nw*2
                    int h = nw * 32 + l15;
                    int off = (h >> 4) * 2048 + (row >> 5) * 512
                            + (((row >> 3) & 3) * 16 + (h & 15)) * 8 + (row & 7);
                    sm[VT_OFF + off] = (_Float16)acc2[i][r];
                }
                {   // v tile nw*2+1
                    int h = nw * 32 + 16 + l15;
                    int off = (h >> 4) * 2048 + (row >> 5) * 512
                            + (((row >> 3) & 3) * 16 + (h & 15)) * 8 + (row & 7);
                    sm[VT_OFF + off] = (_Float16)acc3[i][r];
                }
            } else {
                {   // k tile t0
                    int h = (t0 - 4) * 16 + l15;
                    int off = (row >> 4) * 1024 + (h >> 5) * 512
                            + (((h >> 3) & 3) * 16 + (row & 15)) * 8 + (h & 7);
                    float v0 = acc0[i][r];
                    _Float16 hh = (_Float16)v0;
                    sm[KH_OFF + off] = hh;
                    sm[KL_OFF + off] = (_Float16)(v0 - (float)hh);
                }
                {   // k tile t1
                    int h = (t1 - 4) * 16 + l15;
                    int off = (row >> 4) * 1024 + (h >> 5) * 512
                            + (((h >> 3) & 3) * 16 + (row & 15)) * 8 + (h & 7);
                    float v0 = acc1[i][r];
                    _Float16 hh = (_Float16)v0;
                    sm[KH_OFF + off] = hh;
                    sm[KL_OFF + off] = (_Float16)(v0 - (float)hh);
                }
            }
        }
    }
    __syncthreads();

    // ================= phase 2: scores (split fp16), softmax (waves 0..6) ============
    f32x4 sacc[7];
    float rsum[4] = {0.f, 0.f, 0.f, 0.f};

    if (wid < 7) {
        #pragma unroll
        for (int j = 0; j < 7; ++j) sacc[j] = (f32x4){0.f,0.f,0.f,0.f};
        #pragma unroll
        for (int kk = 0; kk < 2; ++kk) {
            half8 qh = *(const half8*)(sm + QH_OFF + wid * 1024 + kk * 512 + lane * 8);
            half8 ql = *(const half8*)(sm + QL_OFF + wid * 1024 + kk * 512 + lane * 8);
            #pragma unroll
            for (int j = 0; j < 7; ++j) {
                half8 kh = *(const half8*)(sm + KH_OFF + j * 1024 + kk * 512 + lane * 8);
                half8 kl = *(const half8*)(sm + KL_OFF + j * 1024 + kk * 512 + lane * 8);
                sacc[j] = __builtin_amdgcn_mfma_f32_16x16x32_f16(qh, kh, sacc[j], 0, 0, 0);
                sacc[j] = __builtin_amdgcn_mfma_f32_16x16x32_f16(ql, kh, sacc[j], 0, 0, 0);
                sacc[j] = __builtin_amdgcn_mfma_f32_16x16x32_f16(qh, kl, sacc[j], 0, 0, 0);
            }
        }
        float rmax[4] = {-1e30f, -1e30f, -1e30f, -1e30f};
        #pragma unroll
        for (int j = 0; j < 7; ++j) {
            int key = j * 16 + l15;
            #pragma unroll
            for (int r = 0; r < 4; ++r) {
                int row = wid * 16 + lg * 4 + r;
                // faithful bug: multiply by sqrt(64)=8; causal + key<100 mask
                float s = (key <= row && key < T_CTX) ? sacc[j][r] * 8.0f : -1e30f;
                sacc[j][r] = s;
                rmax[r] = fmaxf(rmax[r], s);
            }
        }
        #pragma unroll
        for (int r = 0; r < 4; ++r) {
            #pragma unroll
            for (int d = 1; d < 16; d <<= 1)
                rmax[r] = fmaxf(rmax[r], __shfl_xor(rmax[r], d, 64));
            rsum[r] = rmax[r];   // stash rmax across the barrier
        }
    }
    __syncthreads();   // all q/k reads done before PS overlays that region

    if (wid < 7) {
        float rmax[4];
        #pragma unroll
        for (int r = 0; r < 4; ++r) { rmax[r] = rsum[r]; rsum[r] = 0.f; }
        #pragma unroll
        for (int j = 0; j < 7; ++j) {
            int key = j * 16 + l15;
            #pragma unroll
            for (int r = 0; r < 4; ++r) {
                float p = __expf(sacc[j][r] - rmax[r]);   // masked -> 0
                rsum[r] += p;
                int a = lg * 4 + r;
                int off = wid * 2048 + (key >> 5) * 512
                        + (((key >> 3) & 3) * 16 + a) * 8 + (key & 7);
                sm[PS_OFF + off] = (_Float16)p;
            }
        }
        #pragma unroll
        for (int r = 0; r < 4; ++r) {                   // zero pad keys 112..127
            int key = 112 + l15;
            int a = lg * 4 + r;
            int off = wid * 2048 + (key >> 5) * 512
                    + (((key >> 3) & 3) * 16 + a) * 8 + (key & 7);
            sm[PS_OFF + off] = (_Float16)0.f;
            #pragma unroll
            for (int d = 1; d < 16; d <<= 1)
                rsum[r] += __shfl_xor(rsum[r], d, 64);
        }
    }
    __syncthreads();

    // ================= phase 3: out = (P @ V) / rowsum (waves 0..6) ===================
    if (wid < 7) {
        f32x4 oacc[4];
        #pragma unroll
        for (int j = 0; j < 4; ++j) oacc[j] = (f32x4){0.f,0.f,0.f,0.f};
        #pragma unroll
        for (int kk = 0; kk < 4; ++kk) {
            half8 pa = *(const half8*)(sm + PS_OFF + wid * 2048 + kk * 512 + lane * 8);
            #pragma unroll
            for (int jh = 0; jh < 4; ++jh) {
                half8 vb = *(const half8*)(sm + VT_OFF + jh * 2048 + kk * 512 + lane * 8);
                oacc[jh] = __builtin_amdgcn_mfma_f32_16x16x32_f16(pa, vb, oacc[jh], 0, 0, 0);
            }
        }
        float rinv[4];
        #pragma unroll
        for (int r = 0; r < 4; ++r) rinv[r] = 1.0f / rsum[r];
        #pragma unroll
        for (int jh = 0; jh < 4; ++jh) {
            #pragma unroll
            for (int r = 0; r < 4; ++r) {
                int t = wid * 16 + lg * 4 + r;
                if (t < T_CTX)
                    out[((size_t)b * T_CTX + t) * H_DIM + jh * 16 + l15] = oacc[jh][r] * rinv[r];
            }
        }
    }
}

extern "C" void kernel_launch(void* const* d_in, const int* in_sizes, int n_in,
                              void* d_out, int out_size, void* d_ws, size_t ws_size,
                              hipStream_t stream) {
    const float* x  = (const float*)d_in[0];
    const float* Wq = (const float*)d_in[1];
    const float* Wk = (const float*)d_in[2];
    const float* Wv = (const float*)d_in[3];

    _Float16* wf_hi = (_Float16*)d_ws;                 // 12*12*64*8 halfs = 147456 B
    _Float16* wf_lo = wf_hi + (size_t)9216 * 8;        // total ws use: 294912 B

    prep_w_kernel<<<36, 256, 0, stream>>>(Wq, Wk, Wv, wf_hi, wf_lo);

    (void)hipFuncSetAttribute((const void*)head_kernel,
                              hipFuncAttributeMaxDynamicSharedMemorySize, SMEM_BYTES);
    head_kernel<<<1024, 512, SMEM_BYTES, stream>>>(x, wf_hi, wf_lo, (float*)d_out);
}